// Round 1
// baseline (3090.350 us; speedup 1.0000x reference)
//
#include <hip/hip_runtime.h>

#define NN 50000
#define FEAT 128

// ---------------- ws layout ----------------
// [0]        int   flag           (1 = int64 indices, 0 = int32)
// [1024]     float dinv[NN]       (200 KB)
// [262144]   float y[NN*FEAT]     (25.6 MB ping buffer)
#define DINV_OFF  1024
#define Y_OFF     262144

// Detect whether edge_index is stored as int64 (high 32-bit words all zero)
__global__ void detect_idx_kernel(const unsigned int* ei32, int* flag) {
    __shared__ int ok;
    if (threadIdx.x == 0) ok = 1;
    __syncthreads();
    if (ei32[2 * threadIdx.x + 1] != 0u) ok = 0;   // benign race: all writers write 0
    __syncthreads();
    if (threadIdx.x == 0) *flag = ok;
}

static __device__ __forceinline__ void load_edge(const void* ei, int is64, int E, int e,
                                                 int& src, int& dst) {
    if (is64) {
        const long long* p = (const long long*)ei;
        src = (int)p[e];
        dst = (int)p[E + e];
    } else {
        const int* p = (const int*)ei;
        src = p[e];
        dst = p[E + e];
    }
}

__global__ void deg_kernel(const void* ei, const int* flag, float* deg, int E) {
    int e = blockIdx.x * blockDim.x + threadIdx.x;
    if (e >= E) return;
    const int is64 = *flag;
    int src, dst;
    load_edge(ei, is64, E, e, src, dst);
    atomicAdd(&deg[dst], 1.0f);
}

__global__ void dinv_kernel(float* deg) {
    int i = blockIdx.x * blockDim.x + threadIdx.x;
    if (i >= NN) return;
    float d = deg[i];
    deg[i] = (d > 0.0f) ? (1.0f / sqrtf(d)) : 0.0f;
}

// One edge handled by 32 consecutive threads; each thread does a float4 (4 feats).
template <bool RELU_IN>
__global__ void conv_kernel(const float* __restrict__ xin, const void* ei, const int* flag,
                            const float* __restrict__ dinv, float* __restrict__ yout, int E) {
    int gid = blockIdx.x * blockDim.x + threadIdx.x;
    int e  = gid >> 5;
    int f4 = gid & 31;
    if (e >= E) return;
    const int is64 = *flag;
    int src, dst;
    load_edge(ei, is64, E, e, src, dst);
    float w = dinv[src] * dinv[dst];
    float4 v = ((const float4*)xin)[src * 32 + f4];
    if (RELU_IN) {
        v.x = fmaxf(v.x, 0.0f);
        v.y = fmaxf(v.y, 0.0f);
        v.z = fmaxf(v.z, 0.0f);
        v.w = fmaxf(v.w, 0.0f);
    }
    float* o = yout + (size_t)dst * FEAT + f4 * 4;
    atomicAdd(o + 0, v.x * w);
    atomicAdd(o + 1, v.y * w);
    atomicAdd(o + 2, v.z * w);
    atomicAdd(o + 3, v.w * w);
}

__global__ void relu_kernel(float4* buf, int n4) {
    int i = blockIdx.x * blockDim.x + threadIdx.x;
    if (i >= n4) return;
    float4 v = buf[i];
    v.x = fmaxf(v.x, 0.0f);
    v.y = fmaxf(v.y, 0.0f);
    v.z = fmaxf(v.z, 0.0f);
    v.w = fmaxf(v.w, 0.0f);
    buf[i] = v;
}

extern "C" void kernel_launch(void* const* d_in, const int* in_sizes, int n_in,
                              void* d_out, int out_size, void* d_ws, size_t ws_size,
                              hipStream_t stream) {
    const float* x  = (const float*)d_in[0];
    const void*  ei = d_in[1];
    const int E = in_sizes[1] / 2;

    float* out  = (float*)d_out;
    char*  ws   = (char*)d_ws;
    int*   flag = (int*)ws;
    float* dinv = (float*)(ws + DINV_OFF);
    float* y    = (float*)(ws + Y_OFF);

    const size_t feat_bytes = (size_t)NN * FEAT * sizeof(float);

    // zero accumulators (must happen every call; harness does not re-poison)
    hipMemsetAsync(dinv, 0, NN * sizeof(float), stream);
    hipMemsetAsync(out, 0, feat_bytes, stream);
    hipMemsetAsync(y, 0, feat_bytes, stream);

    // detect int64 vs int32 edge storage
    detect_idx_kernel<<<1, 256, 0, stream>>>((const unsigned int*)ei, flag);

    // degree + dinv
    deg_kernel<<<(E + 255) / 256, 256, 0, stream>>>(ei, flag, dinv, E);
    dinv_kernel<<<(NN + 255) / 256, 256, 0, stream>>>(dinv);

    const int conv_blocks = (int)(((size_t)E * 32 + 255) / 256);

    // layer 1: x -> out (no relu on input)
    conv_kernel<false><<<conv_blocks, 256, 0, stream>>>(x, ei, flag, dinv, out, E);
    // layer 2: relu(out) -> y
    conv_kernel<true><<<conv_blocks, 256, 0, stream>>>(out, ei, flag, dinv, y, E);
    // re-zero out, then layer 3: relu(y) -> out
    hipMemsetAsync(out, 0, feat_bytes, stream);
    conv_kernel<true><<<conv_blocks, 256, 0, stream>>>(y, ei, flag, dinv, out, E);
    // final relu in place
    relu_kernel<<<(out_size / 4 + 255) / 256, 256, 0, stream>>>((float4*)out, out_size / 4);
}

// Round 2
// 322.277 us; speedup vs baseline: 9.5891x; 9.5891x over previous
//
#include <hip/hip_runtime.h>

#define NN 50000
#define FEAT 128

// Detect whether edge_index is stored as int64 (high 32-bit words all zero)
__global__ void detect_idx_kernel(const unsigned int* ei32, int* flag) {
    __shared__ int ok;
    if (threadIdx.x == 0) ok = 1;
    __syncthreads();
    if (ei32[2 * threadIdx.x + 1] != 0u) ok = 0;   // benign race: all writers write 0
    __syncthreads();
    if (threadIdx.x == 0) *flag = ok;
}

static __device__ __forceinline__ void load_edge(const void* ei, int is64, int E, int e,
                                                 int& src, int& dst) {
    if (is64) {
        const long long* p = (const long long*)ei;
        src = (int)p[e];
        dst = (int)p[E + e];
    } else {
        const int* p = (const int*)ei;
        src = p[e];
        dst = p[E + e];
    }
}

// ---------------- CSR build ----------------
__global__ void hist_kernel(const void* ei, const int* flag, int* hist, int E) {
    int e = blockIdx.x * blockDim.x + threadIdx.x;
    if (e >= E) return;
    int src, dst;
    load_edge(ei, *flag, E, e, src, dst);
    atomicAdd(&hist[dst], 1);
}

__global__ void dinv_from_hist_kernel(const int* hist, float* dinv) {
    int i = blockIdx.x * blockDim.x + threadIdx.x;
    if (i >= NN) return;
    int d = hist[i];
    dinv[i] = (d > 0) ? (1.0f / sqrtf((float)d)) : 0.0f;
}

// single-block exclusive scan over n entries -> row_ptr[0..n], cursor copy
__global__ void scan_kernel(const int* hist, int* row_ptr, int* cursor, int n) {
    __shared__ int sdata[1024];
    __shared__ int soff;
    if (threadIdx.x == 0) soff = 0;
    __syncthreads();
    for (int base = 0; base < n; base += 1024) {
        int i = base + (int)threadIdx.x;
        int v = (i < n) ? hist[i] : 0;
        sdata[threadIdx.x] = v;
        __syncthreads();
        for (int d = 1; d < 1024; d <<= 1) {
            int t = (threadIdx.x >= (unsigned)d) ? sdata[threadIdx.x - d] : 0;
            __syncthreads();
            sdata[threadIdx.x] += t;
            __syncthreads();
        }
        int incl = sdata[threadIdx.x];
        int excl = incl - v;
        if (i < n) {
            row_ptr[i] = soff + excl;
            cursor[i]  = soff + excl;
        }
        __syncthreads();
        if (threadIdx.x == 1023) soff += incl;  // chunk total
        __syncthreads();
    }
    if (threadIdx.x == 0) row_ptr[n] = soff;
}

__global__ void scatter_kernel(const void* ei, const int* flag, int* cursor, int* col, int E) {
    int e = blockIdx.x * blockDim.x + threadIdx.x;
    if (e >= E) return;
    int src, dst;
    load_edge(ei, *flag, E, e, src, dst);
    int pos = atomicAdd(&cursor[dst], 1);
    col[pos] = src;
}

// ---------------- CSR conv: 32 threads per node, float4 per thread ----------------
template <bool RELU_IN, bool RELU_OUT>
__global__ void conv_csr_kernel(const float* __restrict__ xin,
                                const int* __restrict__ row_ptr,
                                const int* __restrict__ col,
                                const float* __restrict__ dinv,
                                float* __restrict__ out) {
    int gid = blockIdx.x * blockDim.x + threadIdx.x;
    int node = gid >> 5;
    int f4   = gid & 31;
    if (node >= NN) return;
    int beg = row_ptr[node];
    int end = row_ptr[node + 1];
    float dd = dinv[node];
    float4 acc = make_float4(0.f, 0.f, 0.f, 0.f);
    for (int e = beg; e < end; ++e) {
        int src = col[e];
        float w = dinv[src] * dd;
        float4 v = ((const float4*)xin)[src * 32 + f4];
        if (RELU_IN) {
            v.x = fmaxf(v.x, 0.0f);
            v.y = fmaxf(v.y, 0.0f);
            v.z = fmaxf(v.z, 0.0f);
            v.w = fmaxf(v.w, 0.0f);
        }
        acc.x += w * v.x;
        acc.y += w * v.y;
        acc.z += w * v.z;
        acc.w += w * v.w;
    }
    if (RELU_OUT) {
        acc.x = fmaxf(acc.x, 0.0f);
        acc.y = fmaxf(acc.y, 0.0f);
        acc.z = fmaxf(acc.z, 0.0f);
        acc.w = fmaxf(acc.w, 0.0f);
    }
    ((float4*)out)[node * 32 + f4] = acc;
}

// ---------------- fallback (atomic) path kernels ----------------
__global__ void deg_kernel(const void* ei, const int* flag, float* deg, int E) {
    int e = blockIdx.x * blockDim.x + threadIdx.x;
    if (e >= E) return;
    int src, dst;
    load_edge(ei, *flag, E, e, src, dst);
    atomicAdd(&deg[dst], 1.0f);
}

__global__ void dinv_kernel(float* deg) {
    int i = blockIdx.x * blockDim.x + threadIdx.x;
    if (i >= NN) return;
    float d = deg[i];
    deg[i] = (d > 0.0f) ? (1.0f / sqrtf(d)) : 0.0f;
}

template <bool RELU_IN>
__global__ void conv_atomic_kernel(const float* __restrict__ xin, const void* ei, const int* flag,
                                   const float* __restrict__ dinv, float* __restrict__ yout, int E) {
    int gid = blockIdx.x * blockDim.x + threadIdx.x;
    int e  = gid >> 5;
    int f4 = gid & 31;
    if (e >= E) return;
    int src, dst;
    load_edge(ei, *flag, E, e, src, dst);
    float w = dinv[src] * dinv[dst];
    float4 v = ((const float4*)xin)[src * 32 + f4];
    if (RELU_IN) {
        v.x = fmaxf(v.x, 0.0f); v.y = fmaxf(v.y, 0.0f);
        v.z = fmaxf(v.z, 0.0f); v.w = fmaxf(v.w, 0.0f);
    }
    float* o = yout + (size_t)dst * FEAT + f4 * 4;
    atomicAdd(o + 0, v.x * w);
    atomicAdd(o + 1, v.y * w);
    atomicAdd(o + 2, v.z * w);
    atomicAdd(o + 3, v.w * w);
}

__global__ void relu_kernel(float4* buf, int n4) {
    int i = blockIdx.x * blockDim.x + threadIdx.x;
    if (i >= n4) return;
    float4 v = buf[i];
    v.x = fmaxf(v.x, 0.0f); v.y = fmaxf(v.y, 0.0f);
    v.z = fmaxf(v.z, 0.0f); v.w = fmaxf(v.w, 0.0f);
    buf[i] = v;
}

extern "C" void kernel_launch(void* const* d_in, const int* in_sizes, int n_in,
                              void* d_out, int out_size, void* d_ws, size_t ws_size,
                              hipStream_t stream) {
    const float* x  = (const float*)d_in[0];
    const void*  ei = d_in[1];
    const int E = in_sizes[1] / 2;

    float* out = (float*)d_out;
    char*  ws  = (char*)d_ws;

    const size_t feat_bytes = (size_t)NN * FEAT * sizeof(float);

    // ws layout (CSR path)
    const size_t OFF_FLAG = 0;
    const size_t OFF_HIST = 1024;
    const size_t OFF_DINV = OFF_HIST + ((size_t)NN * 4 + 255 & ~255ull);
    const size_t OFF_ROWP = OFF_DINV + ((size_t)NN * 4 + 255 & ~255ull);
    const size_t OFF_CURS = OFF_ROWP + (((size_t)NN + 1) * 4 + 255 & ~255ull);
    const size_t OFF_COL  = OFF_CURS + ((size_t)NN * 4 + 255 & ~255ull);
    const size_t OFF_Y    = OFF_COL + ((size_t)E * 4 + 255 & ~255ull);
    const size_t NEEDED   = OFF_Y + feat_bytes;

    int*   flag = (int*)(ws + OFF_FLAG);

    if (ws_size >= NEEDED) {
        int*   hist = (int*)(ws + OFF_HIST);
        float* dinv = (float*)(ws + OFF_DINV);
        int*   rowp = (int*)(ws + OFF_ROWP);
        int*   curs = (int*)(ws + OFF_CURS);
        int*   col  = (int*)(ws + OFF_COL);
        float* y    = (float*)(ws + OFF_Y);

        hipMemsetAsync(hist, 0, NN * sizeof(int), stream);
        detect_idx_kernel<<<1, 256, 0, stream>>>((const unsigned int*)ei, flag);

        hist_kernel<<<(E + 255) / 256, 256, 0, stream>>>(ei, flag, hist, E);
        dinv_from_hist_kernel<<<(NN + 255) / 256, 256, 0, stream>>>(hist, dinv);
        scan_kernel<<<1, 1024, 0, stream>>>(hist, rowp, curs, NN);
        scatter_kernel<<<(E + 255) / 256, 256, 0, stream>>>(ei, flag, curs, col, E);

        const int conv_blocks = (NN * 32 + 255) / 256;
        // layer 1: x -> y       (no relu-in, no relu-out)
        conv_csr_kernel<false, false><<<conv_blocks, 256, 0, stream>>>(x, rowp, col, dinv, y);
        // layer 2: relu(y) -> out
        conv_csr_kernel<true, false><<<conv_blocks, 256, 0, stream>>>(y, rowp, col, dinv, out);
        // layer 3: relu(out) -> y ... write directly to out? need src!=dst buffer
        conv_csr_kernel<true, true><<<conv_blocks, 256, 0, stream>>>(out, rowp, col, dinv, y);
        // copy final y -> out
        hipMemcpyAsync(out, y, feat_bytes, hipMemcpyDeviceToDevice, stream);
    } else {
        // fallback: previous atomic implementation
        float* dinv = (float*)(ws + 1024);
        float* y    = (float*)(ws + 262144);

        hipMemsetAsync(dinv, 0, NN * sizeof(float), stream);
        hipMemsetAsync(out, 0, feat_bytes, stream);
        hipMemsetAsync(y, 0, feat_bytes, stream);

        detect_idx_kernel<<<1, 256, 0, stream>>>((const unsigned int*)ei, flag);
        deg_kernel<<<(E + 255) / 256, 256, 0, stream>>>(ei, flag, dinv, E);
        dinv_kernel<<<(NN + 255) / 256, 256, 0, stream>>>(dinv);

        const int conv_blocks = (int)(((size_t)E * 32 + 255) / 256);
        conv_atomic_kernel<false><<<conv_blocks, 256, 0, stream>>>(x, ei, flag, dinv, out, E);
        conv_atomic_kernel<true><<<conv_blocks, 256, 0, stream>>>(out, ei, flag, dinv, y, E);
        hipMemsetAsync(out, 0, feat_bytes, stream);
        conv_atomic_kernel<true><<<conv_blocks, 256, 0, stream>>>(y, ei, flag, dinv, out, E);
        relu_kernel<<<(out_size / 4 + 255) / 256, 256, 0, stream>>>((float4*)out, out_size / 4);
    }
}

// Round 3
// 238.171 us; speedup vs baseline: 12.9753x; 1.3531x over previous
//
#include <hip/hip_runtime.h>

#define NN 50000
#define FEAT 128

// Detect whether edge_index is stored as int64 (high 32-bit words all zero)
__global__ void detect_idx_kernel(const unsigned int* ei32, int* flag) {
    __shared__ int ok;
    if (threadIdx.x == 0) ok = 1;
    __syncthreads();
    if (ei32[2 * threadIdx.x + 1] != 0u) ok = 0;   // benign race: all writers write 0
    __syncthreads();
    if (threadIdx.x == 0) *flag = ok;
}

static __device__ __forceinline__ void load_edge(const void* ei, int is64, int E, int e,
                                                 int& src, int& dst) {
    if (is64) {
        const long long* p = (const long long*)ei;
        src = (int)p[e];
        dst = (int)p[E + e];
    } else {
        const int* p = (const int*)ei;
        src = p[e];
        dst = p[E + e];
    }
}

// ---------------- CSR build ----------------
__global__ void hist_kernel(const void* ei, const int* flag, int* hist, int E) {
    int e = blockIdx.x * blockDim.x + threadIdx.x;
    if (e >= E) return;
    int src, dst;
    load_edge(ei, *flag, E, e, src, dst);
    atomicAdd(&hist[dst], 1);
}

// phase 1: per-block (256) inclusive scan -> exclusive local offsets + block sums.
// Also computes dinv[i] from hist[i] (fused).
__global__ void scan_local_kernel(const int* __restrict__ hist, int* __restrict__ local_excl,
                                  int* __restrict__ bsum, float* __restrict__ dinv, int n) {
    __shared__ int sdata[256];
    int i = blockIdx.x * 256 + threadIdx.x;
    int v = (i < n) ? hist[i] : 0;
    if (i < n) dinv[i] = (v > 0) ? rsqrtf((float)v) : 0.0f;
    sdata[threadIdx.x] = v;
    __syncthreads();
    for (int d = 1; d < 256; d <<= 1) {
        int t = (threadIdx.x >= (unsigned)d) ? sdata[threadIdx.x - d] : 0;
        __syncthreads();
        sdata[threadIdx.x] += t;
        __syncthreads();
    }
    if (i < n) local_excl[i] = sdata[threadIdx.x] - v;
    if (threadIdx.x == 255) bsum[blockIdx.x] = sdata[255];
}

// phase 2: single-block exclusive scan of block sums (nb <= 1024)
__global__ void scan_bsum_kernel(int* bsum, int nb) {
    __shared__ int sdata[1024];
    int v = ((int)threadIdx.x < nb) ? bsum[threadIdx.x] : 0;
    sdata[threadIdx.x] = v;
    __syncthreads();
    for (int d = 1; d < 1024; d <<= 1) {
        int t = (threadIdx.x >= (unsigned)d) ? sdata[threadIdx.x - d] : 0;
        __syncthreads();
        sdata[threadIdx.x] += t;
        __syncthreads();
    }
    if ((int)threadIdx.x < nb) bsum[threadIdx.x] = sdata[threadIdx.x] - v;
}

// phase 3: add block offsets -> row_ptr + cursor; thread 0 writes row_ptr[n]=E
__global__ void scan_add_kernel(const int* __restrict__ local_excl, const int* __restrict__ bsum,
                                int* __restrict__ rowp, int* __restrict__ curs, int n, int E) {
    int i = blockIdx.x * 256 + threadIdx.x;
    if (i < n) {
        int r = local_excl[i] + bsum[i >> 8];
        rowp[i] = r;
        curs[i] = r;
    }
    if (i == 0) rowp[n] = E;
}

// scatter src index AND precomputed edge weight
__global__ void scatter_kernel(const void* ei, const int* flag, int* cursor,
                               int* __restrict__ col, float* __restrict__ wgt,
                               const float* __restrict__ dinv, int E) {
    int e = blockIdx.x * blockDim.x + threadIdx.x;
    if (e >= E) return;
    int src, dst;
    load_edge(ei, *flag, E, e, src, dst);
    int pos = atomicAdd(&cursor[dst], 1);
    col[pos] = src;
    wgt[pos] = dinv[src] * dinv[dst];
}

// ---------------- CSR conv: 32 threads per node, float4 per thread ----------------
template <bool RELU_IN, bool RELU_OUT>
__global__ void conv_csr_kernel(const float* __restrict__ xin,
                                const int* __restrict__ row_ptr,
                                const int* __restrict__ col,
                                const float* __restrict__ wgt,
                                float* __restrict__ out) {
    int gid = blockIdx.x * blockDim.x + threadIdx.x;
    int node = gid >> 5;
    int f4   = gid & 31;
    if (node >= NN) return;
    int beg = row_ptr[node];
    int end = row_ptr[node + 1];
    float4 acc = make_float4(0.f, 0.f, 0.f, 0.f);
    for (int e = beg; e < end; ++e) {
        int src = col[e];
        float w = wgt[e];
        float4 v = ((const float4*)xin)[src * 32 + f4];
        if (RELU_IN) {
            v.x = fmaxf(v.x, 0.0f);
            v.y = fmaxf(v.y, 0.0f);
            v.z = fmaxf(v.z, 0.0f);
            v.w = fmaxf(v.w, 0.0f);
        }
        acc.x += w * v.x;
        acc.y += w * v.y;
        acc.z += w * v.z;
        acc.w += w * v.w;
    }
    if (RELU_OUT) {
        acc.x = fmaxf(acc.x, 0.0f);
        acc.y = fmaxf(acc.y, 0.0f);
        acc.z = fmaxf(acc.z, 0.0f);
        acc.w = fmaxf(acc.w, 0.0f);
    }
    ((float4*)out)[node * 32 + f4] = acc;
}

// ---------------- fallback (atomic) path kernels ----------------
__global__ void deg_kernel(const void* ei, const int* flag, float* deg, int E) {
    int e = blockIdx.x * blockDim.x + threadIdx.x;
    if (e >= E) return;
    int src, dst;
    load_edge(ei, *flag, E, e, src, dst);
    atomicAdd(&deg[dst], 1.0f);
}

__global__ void dinv_kernel(float* deg) {
    int i = blockIdx.x * blockDim.x + threadIdx.x;
    if (i >= NN) return;
    float d = deg[i];
    deg[i] = (d > 0.0f) ? (1.0f / sqrtf(d)) : 0.0f;
}

template <bool RELU_IN>
__global__ void conv_atomic_kernel(const float* __restrict__ xin, const void* ei, const int* flag,
                                   const float* __restrict__ dinv, float* __restrict__ yout, int E) {
    int gid = blockIdx.x * blockDim.x + threadIdx.x;
    int e  = gid >> 5;
    int f4 = gid & 31;
    if (e >= E) return;
    int src, dst;
    load_edge(ei, *flag, E, e, src, dst);
    float w = dinv[src] * dinv[dst];
    float4 v = ((const float4*)xin)[src * 32 + f4];
    if (RELU_IN) {
        v.x = fmaxf(v.x, 0.0f); v.y = fmaxf(v.y, 0.0f);
        v.z = fmaxf(v.z, 0.0f); v.w = fmaxf(v.w, 0.0f);
    }
    float* o = yout + (size_t)dst * FEAT + f4 * 4;
    atomicAdd(o + 0, v.x * w);
    atomicAdd(o + 1, v.y * w);
    atomicAdd(o + 2, v.z * w);
    atomicAdd(o + 3, v.w * w);
}

__global__ void relu_kernel(float4* buf, int n4) {
    int i = blockIdx.x * blockDim.x + threadIdx.x;
    if (i >= n4) return;
    float4 v = buf[i];
    v.x = fmaxf(v.x, 0.0f); v.y = fmaxf(v.y, 0.0f);
    v.z = fmaxf(v.z, 0.0f); v.w = fmaxf(v.w, 0.0f);
    buf[i] = v;
}

extern "C" void kernel_launch(void* const* d_in, const int* in_sizes, int n_in,
                              void* d_out, int out_size, void* d_ws, size_t ws_size,
                              hipStream_t stream) {
    const float* x  = (const float*)d_in[0];
    const void*  ei = d_in[1];
    const int E = in_sizes[1] / 2;

    float* out = (float*)d_out;
    char*  ws  = (char*)d_ws;

    const size_t feat_bytes = (size_t)NN * FEAT * sizeof(float);
    const int NB = (NN + 255) / 256;   // 196 scan blocks

    // ws layout (CSR path)
    const size_t OFF_FLAG = 0;
    const size_t OFF_HIST = 1024;
    const size_t OFF_DINV = OFF_HIST + (((size_t)NN * 4 + 255) & ~255ull);
    const size_t OFF_ROWP = OFF_DINV + (((size_t)NN * 4 + 255) & ~255ull);
    const size_t OFF_CURS = OFF_ROWP + ((((size_t)NN + 1) * 4 + 255) & ~255ull);
    const size_t OFF_BSUM = OFF_CURS + (((size_t)NN * 4 + 255) & ~255ull);
    const size_t OFF_COL  = OFF_BSUM + ((1024 * 4 + 255) & ~255ull);
    const size_t OFF_WGT  = OFF_COL + (((size_t)E * 4 + 255) & ~255ull);
    const size_t OFF_Y    = OFF_WGT + (((size_t)E * 4 + 255) & ~255ull);
    const size_t NEEDED   = OFF_Y + feat_bytes;

    int* flag = (int*)(ws + OFF_FLAG);

    if (ws_size >= NEEDED) {
        int*   hist = (int*)(ws + OFF_HIST);
        float* dinv = (float*)(ws + OFF_DINV);
        int*   rowp = (int*)(ws + OFF_ROWP);
        int*   curs = (int*)(ws + OFF_CURS);
        int*   bsum = (int*)(ws + OFF_BSUM);
        int*   col  = (int*)(ws + OFF_COL);
        float* wgt  = (float*)(ws + OFF_WGT);
        float* y    = (float*)(ws + OFF_Y);

        hipMemsetAsync(hist, 0, NN * sizeof(int), stream);
        detect_idx_kernel<<<1, 256, 0, stream>>>((const unsigned int*)ei, flag);

        hist_kernel<<<(E + 255) / 256, 256, 0, stream>>>(ei, flag, hist, E);
        // hierarchical scan (rowp doubles as local_excl scratch) + fused dinv
        scan_local_kernel<<<NB, 256, 0, stream>>>(hist, rowp, bsum, dinv, NN);
        scan_bsum_kernel<<<1, 1024, 0, stream>>>(bsum, NB);
        scan_add_kernel<<<NB, 256, 0, stream>>>(rowp, bsum, rowp, curs, NN, E);
        scatter_kernel<<<(E + 255) / 256, 256, 0, stream>>>(ei, flag, curs, col, wgt, dinv, E);

        const int conv_blocks = (NN * 32 + 255) / 256;
        // layer 1: x -> out
        conv_csr_kernel<false, false><<<conv_blocks, 256, 0, stream>>>(x, rowp, col, wgt, out);
        // layer 2: relu(out) -> y
        conv_csr_kernel<true, false><<<conv_blocks, 256, 0, stream>>>(out, rowp, col, wgt, y);
        // layer 3: relu(y) -> out (+ final relu fused)
        conv_csr_kernel<true, true><<<conv_blocks, 256, 0, stream>>>(y, rowp, col, wgt, out);
    } else {
        // fallback: atomic implementation
        float* dinv = (float*)(ws + 1024);
        float* y    = (float*)(ws + 262144);

        hipMemsetAsync(dinv, 0, NN * sizeof(float), stream);
        hipMemsetAsync(out, 0, feat_bytes, stream);
        hipMemsetAsync(y, 0, feat_bytes, stream);

        detect_idx_kernel<<<1, 256, 0, stream>>>((const unsigned int*)ei, flag);
        deg_kernel<<<(E + 255) / 256, 256, 0, stream>>>(ei, flag, dinv, E);
        dinv_kernel<<<(NN + 255) / 256, 256, 0, stream>>>(dinv);

        const int conv_blocks = (int)(((size_t)E * 32 + 255) / 256);
        conv_atomic_kernel<false><<<conv_blocks, 256, 0, stream>>>(x, ei, flag, dinv, out, E);
        conv_atomic_kernel<true><<<conv_blocks, 256, 0, stream>>>(out, ei, flag, dinv, y, E);
        hipMemsetAsync(out, 0, feat_bytes, stream);
        conv_atomic_kernel<true><<<conv_blocks, 256, 0, stream>>>(y, ei, flag, dinv, out, E);
        relu_kernel<<<(out_size / 4 + 255) / 256, 256, 0, stream>>>((float4*)out, out_size / 4);
    }
}

// Round 4
// 210.208 us; speedup vs baseline: 14.7014x; 1.1330x over previous
//
#include <hip/hip_runtime.h>

#define NN 50000
#define FEAT 128

// Detect whether edge_index is stored as int64 (high 32-bit words all zero)
__global__ void detect_idx_kernel(const unsigned int* ei32, int* flag) {
    __shared__ int ok;
    if (threadIdx.x == 0) ok = 1;
    __syncthreads();
    if (ei32[2 * threadIdx.x + 1] != 0u) ok = 0;   // benign race: all writers write 0
    __syncthreads();
    if (threadIdx.x == 0) *flag = ok;
}

static __device__ __forceinline__ void load_edge(const void* ei, int is64, int E, int e,
                                                 int& src, int& dst) {
    if (is64) {
        const long long* p = (const long long*)ei;
        src = (int)p[e];
        dst = (int)p[E + e];
    } else {
        const int* p = (const int*)ei;
        src = p[e];
        dst = p[E + e];
    }
}

// ---------------- CSR build ----------------
__global__ void hist_kernel(const void* ei, const int* flag, int* hist, int E) {
    int e = blockIdx.x * blockDim.x + threadIdx.x;
    if (e >= E) return;
    int src, dst;
    load_edge(ei, *flag, E, e, src, dst);
    atomicAdd(&hist[dst], 1);
}

// phase 1: per-block (256) inclusive scan -> exclusive local offsets + block sums + dinv
__global__ void scan_local_kernel(const int* __restrict__ hist, int* __restrict__ local_excl,
                                  int* __restrict__ bsum, float* __restrict__ dinv, int n) {
    __shared__ int sdata[256];
    int i = blockIdx.x * 256 + threadIdx.x;
    int v = (i < n) ? hist[i] : 0;
    if (i < n) dinv[i] = (v > 0) ? rsqrtf((float)v) : 0.0f;
    sdata[threadIdx.x] = v;
    __syncthreads();
    for (int d = 1; d < 256; d <<= 1) {
        int t = (threadIdx.x >= (unsigned)d) ? sdata[threadIdx.x - d] : 0;
        __syncthreads();
        sdata[threadIdx.x] += t;
        __syncthreads();
    }
    if (i < n) local_excl[i] = sdata[threadIdx.x] - v;
    if (threadIdx.x == 255) bsum[blockIdx.x] = sdata[255];
}

// phase 2: single-block exclusive scan of block sums (nb <= 1024)
__global__ void scan_bsum_kernel(int* bsum, int nb) {
    __shared__ int sdata[1024];
    int v = ((int)threadIdx.x < nb) ? bsum[threadIdx.x] : 0;
    sdata[threadIdx.x] = v;
    __syncthreads();
    for (int d = 1; d < 1024; d <<= 1) {
        int t = (threadIdx.x >= (unsigned)d) ? sdata[threadIdx.x - d] : 0;
        __syncthreads();
        sdata[threadIdx.x] += t;
        __syncthreads();
    }
    if ((int)threadIdx.x < nb) bsum[threadIdx.x] = sdata[threadIdx.x] - v;
}

// phase 3: add block offsets -> row_ptr + cursor; thread 0 writes row_ptr[n]=E
__global__ void scan_add_kernel(const int* __restrict__ local_excl, const int* __restrict__ bsum,
                                int* __restrict__ rowp, int* __restrict__ curs, int n, int E) {
    int i = blockIdx.x * 256 + threadIdx.x;
    if (i < n) {
        int r = local_excl[i] + bsum[i >> 8];
        rowp[i] = r;
        curs[i] = r;
    }
    if (i == 0) rowp[n] = E;
}

// scatter {src, weight} as one int2
__global__ void scatter_kernel(const void* ei, const int* flag, int* cursor,
                               int2* __restrict__ edge,
                               const float* __restrict__ dinv, int E) {
    int e = blockIdx.x * blockDim.x + threadIdx.x;
    if (e >= E) return;
    int src, dst;
    load_edge(ei, *flag, E, e, src, dst);
    int pos = atomicAdd(&cursor[dst], 1);
    float w = dinv[src] * dinv[dst];
    edge[pos] = make_int2(src, __float_as_int(w));
}

static __device__ __forceinline__ float4 relu4(float4 v) {
    v.x = fmaxf(v.x, 0.0f); v.y = fmaxf(v.y, 0.0f);
    v.z = fmaxf(v.z, 0.0f); v.w = fmaxf(v.w, 0.0f);
    return v;
}

static __device__ __forceinline__ void fma4(float4& a, float w, float4 v) {
    a.x += w * v.x; a.y += w * v.y; a.z += w * v.z; a.w += w * v.w;
}

// ---------------- CSR conv: 32 threads/node, float4/thread, 4-way edge ILP ----------------
template <bool RELU_IN, bool RELU_OUT>
__global__ void conv_csr_kernel(const float* __restrict__ xin,
                                const int* __restrict__ row_ptr,
                                const int2* __restrict__ edge,
                                float* __restrict__ out) {
    int gid = blockIdx.x * blockDim.x + threadIdx.x;
    int node = gid >> 5;
    int f4   = gid & 31;
    if (node >= NN) return;
    int beg = row_ptr[node];
    int end = row_ptr[node + 1];
    const float4* xv = (const float4*)xin;

    float4 a0 = make_float4(0.f, 0.f, 0.f, 0.f);
    float4 a1 = a0, a2 = a0, a3 = a0;

    int e = beg;
    for (; e + 4 <= end; e += 4) {
        int2 e0 = edge[e + 0];
        int2 e1 = edge[e + 1];
        int2 e2 = edge[e + 2];
        int2 e3 = edge[e + 3];
        float4 v0 = xv[e0.x * 32 + f4];
        float4 v1 = xv[e1.x * 32 + f4];
        float4 v2 = xv[e2.x * 32 + f4];
        float4 v3 = xv[e3.x * 32 + f4];
        if (RELU_IN) { v0 = relu4(v0); v1 = relu4(v1); v2 = relu4(v2); v3 = relu4(v3); }
        fma4(a0, __int_as_float(e0.y), v0);
        fma4(a1, __int_as_float(e1.y), v1);
        fma4(a2, __int_as_float(e2.y), v2);
        fma4(a3, __int_as_float(e3.y), v3);
    }
    for (; e < end; ++e) {
        int2 ed = edge[e];
        float4 v = xv[ed.x * 32 + f4];
        if (RELU_IN) v = relu4(v);
        fma4(a0, __int_as_float(ed.y), v);
    }

    float4 acc;
    acc.x = (a0.x + a1.x) + (a2.x + a3.x);
    acc.y = (a0.y + a1.y) + (a2.y + a3.y);
    acc.z = (a0.z + a1.z) + (a2.z + a3.z);
    acc.w = (a0.w + a1.w) + (a2.w + a3.w);
    if (RELU_OUT) acc = relu4(acc);
    ((float4*)out)[node * 32 + f4] = acc;
}

// ---------------- fallback (atomic) path kernels ----------------
__global__ void deg_kernel(const void* ei, const int* flag, float* deg, int E) {
    int e = blockIdx.x * blockDim.x + threadIdx.x;
    if (e >= E) return;
    int src, dst;
    load_edge(ei, *flag, E, e, src, dst);
    atomicAdd(&deg[dst], 1.0f);
}

__global__ void dinv_kernel(float* deg) {
    int i = blockIdx.x * blockDim.x + threadIdx.x;
    if (i >= NN) return;
    float d = deg[i];
    deg[i] = (d > 0.0f) ? (1.0f / sqrtf(d)) : 0.0f;
}

template <bool RELU_IN>
__global__ void conv_atomic_kernel(const float* __restrict__ xin, const void* ei, const int* flag,
                                   const float* __restrict__ dinv, float* __restrict__ yout, int E) {
    int gid = blockIdx.x * blockDim.x + threadIdx.x;
    int e  = gid >> 5;
    int f4 = gid & 31;
    if (e >= E) return;
    int src, dst;
    load_edge(ei, *flag, E, e, src, dst);
    float w = dinv[src] * dinv[dst];
    float4 v = ((const float4*)xin)[src * 32 + f4];
    if (RELU_IN) v = relu4(v);
    float* o = yout + (size_t)dst * FEAT + f4 * 4;
    atomicAdd(o + 0, v.x * w);
    atomicAdd(o + 1, v.y * w);
    atomicAdd(o + 2, v.z * w);
    atomicAdd(o + 3, v.w * w);
}

__global__ void relu_kernel(float4* buf, int n4) {
    int i = blockIdx.x * blockDim.x + threadIdx.x;
    if (i >= n4) return;
    buf[i] = relu4(buf[i]);
}

extern "C" void kernel_launch(void* const* d_in, const int* in_sizes, int n_in,
                              void* d_out, int out_size, void* d_ws, size_t ws_size,
                              hipStream_t stream) {
    const float* x  = (const float*)d_in[0];
    const void*  ei = d_in[1];
    const int E = in_sizes[1] / 2;

    float* out = (float*)d_out;
    char*  ws  = (char*)d_ws;

    const size_t feat_bytes = (size_t)NN * FEAT * sizeof(float);
    const int NB = (NN + 255) / 256;

    // ws layout (CSR path)
    const size_t OFF_FLAG = 0;
    const size_t OFF_HIST = 1024;
    const size_t OFF_DINV = OFF_HIST + (((size_t)NN * 4 + 255) & ~255ull);
    const size_t OFF_ROWP = OFF_DINV + (((size_t)NN * 4 + 255) & ~255ull);
    const size_t OFF_CURS = OFF_ROWP + ((((size_t)NN + 1) * 4 + 255) & ~255ull);
    const size_t OFF_BSUM = OFF_CURS + (((size_t)NN * 4 + 255) & ~255ull);
    const size_t OFF_EDG  = OFF_BSUM + ((1024 * 4 + 255) & ~255ull);
    const size_t OFF_Y    = OFF_EDG + (((size_t)E * 8 + 255) & ~255ull);
    const size_t NEEDED   = OFF_Y + feat_bytes;

    int* flag = (int*)(ws + OFF_FLAG);

    if (ws_size >= NEEDED) {
        int*   hist = (int*)(ws + OFF_HIST);
        float* dinv = (float*)(ws + OFF_DINV);
        int*   rowp = (int*)(ws + OFF_ROWP);
        int*   curs = (int*)(ws + OFF_CURS);
        int*   bsum = (int*)(ws + OFF_BSUM);
        int2*  edge = (int2*)(ws + OFF_EDG);
        float* y    = (float*)(ws + OFF_Y);

        hipMemsetAsync(hist, 0, NN * sizeof(int), stream);
        detect_idx_kernel<<<1, 256, 0, stream>>>((const unsigned int*)ei, flag);

        hist_kernel<<<(E + 255) / 256, 256, 0, stream>>>(ei, flag, hist, E);
        scan_local_kernel<<<NB, 256, 0, stream>>>(hist, rowp, bsum, dinv, NN);
        scan_bsum_kernel<<<1, 1024, 0, stream>>>(bsum, NB);
        scan_add_kernel<<<NB, 256, 0, stream>>>(rowp, bsum, rowp, curs, NN, E);
        scatter_kernel<<<(E + 255) / 256, 256, 0, stream>>>(ei, flag, curs, edge, dinv, E);

        const int conv_blocks = (NN * 32 + 255) / 256;
        // layer 1: x -> out
        conv_csr_kernel<false, false><<<conv_blocks, 256, 0, stream>>>(x, rowp, edge, out);
        // layer 2: relu(out) -> y
        conv_csr_kernel<true, false><<<conv_blocks, 256, 0, stream>>>(out, rowp, edge, y);
        // layer 3: relu(y) -> out (+ final relu fused)
        conv_csr_kernel<true, true><<<conv_blocks, 256, 0, stream>>>(y, rowp, edge, out);
    } else {
        // fallback: atomic implementation
        float* dinv = (float*)(ws + 1024);
        float* y    = (float*)(ws + 262144);

        hipMemsetAsync(dinv, 0, NN * sizeof(float), stream);
        hipMemsetAsync(out, 0, feat_bytes, stream);
        hipMemsetAsync(y, 0, feat_bytes, stream);

        detect_idx_kernel<<<1, 256, 0, stream>>>((const unsigned int*)ei, flag);
        deg_kernel<<<(E + 255) / 256, 256, 0, stream>>>(ei, flag, dinv, E);
        dinv_kernel<<<(NN + 255) / 256, 256, 0, stream>>>(dinv);

        const int conv_blocks = (int)(((size_t)E * 32 + 255) / 256);
        conv_atomic_kernel<false><<<conv_blocks, 256, 0, stream>>>(x, ei, flag, dinv, out, E);
        conv_atomic_kernel<true><<<conv_blocks, 256, 0, stream>>>(out, ei, flag, dinv, y, E);
        hipMemsetAsync(out, 0, feat_bytes, stream);
        conv_atomic_kernel<true><<<conv_blocks, 256, 0, stream>>>(y, ei, flag, dinv, out, E);
        relu_kernel<<<(out_size / 4 + 255) / 256, 256, 0, stream>>>((float4*)out, out_size / 4);
    }
}